// Round 21
// baseline (70.978 us; speedup 1.0000x reference)
//
#include <hip/hip_runtime.h>
#include <math.h>

#define CCH 256
#define NN  4096
#define NHEAD 8
#define CONDD 512

typedef __attribute__((ext_vector_type(8))) short short8;
typedef __attribute__((ext_vector_type(4))) float f32x4;
typedef __attribute__((ext_vector_type(16))) float f32x16;

static __device__ __forceinline__ short f2bf(float f) {
    union { float f; uint32_t u; } v; v.f = f;
    uint32_t r = v.u + 0x7fffu + ((v.u >> 16) & 1u);   // RNE
    return (short)(r >> 16);
}

static __device__ __forceinline__ uint32_t cvt_pk_bf16(float a, float b) {
    uint32_t r;
    asm("v_cvt_pk_bf16_f32 %0, %1, %2" : "=v"(r) : "v"(a), "v"(b));
    return r;
}

// ---------------- fused front: group stats | weight conv | adagn linear ----------------
__global__ __launch_bounds__(256) void front_fused(const float* __restrict__ x,
                                                   const float* __restrict__ cond,
                                                   const float* __restrict__ w_scale,
                                                   const float* __restrict__ b_scale,
                                                   const float* __restrict__ w_shift,
                                                   const float* __restrict__ b_shift,
                                                   const float* __restrict__ wq,
                                                   const float* __restrict__ wo,
                                                   float* __restrict__ partial,
                                                   float* __restrict__ scale,
                                                   float* __restrict__ shift,
                                                   short* __restrict__ wqb,
                                                   short* __restrict__ wob) {
    __shared__ float rs[4], rss[4];
    int bb = blockIdx.x;
    int t = threadIdx.x;
    if (bb < 256) {
        const float4* p = (const float4*)(x + bb * 4096);
        float s = 0.f, ss = 0.f;
        for (int k = t; k < 1024; k += 256) {
            float4 v = p[k];
            s += v.x + v.y + v.z + v.w;
            ss += v.x * v.x + v.y * v.y + v.z * v.z + v.w * v.w;
        }
        #pragma unroll
        for (int off = 32; off; off >>= 1) { s += __shfl_xor(s, off); ss += __shfl_xor(ss, off); }
        int wid = t >> 6;
        if ((t & 63) == 0) { rs[wid] = s; rss[wid] = ss; }
        __syncthreads();
        if (t == 0) {
            partial[2 * bb] = rs[0] + rs[1] + rs[2] + rs[3];
            partial[2 * bb + 1] = rss[0] + rss[1] + rss[2] + rss[3];
        }
    } else if (bb < 1280) {
        int idx = (bb - 256) * 256 + t;
        if (idx < 196608) wqb[idx] = f2bf(wq[idx]);
        else              wob[idx - 196608] = f2bf(wo[idx - 196608]);
    } else {
        int o = (bb - 1280) * 4 + (t >> 6);
        int lane = t & 63;
        float ds = 0.f, dh = 0.f;
        for (int k = lane; k < CONDD; k += 64) {
            float cv = cond[k];
            ds += cv * w_scale[o * CONDD + k];
            dh += cv * w_shift[o * CONDD + k];
        }
        #pragma unroll
        for (int off = 32; off; off >>= 1) { ds += __shfl_xor(ds, off); dh += __shfl_xor(dh, off); }
        if (lane == 0) { scale[o] = ds + b_scale[o]; shift[o] = dh + b_shift[o]; }
    }
}

// ---------------- normalize + affine -> bf16 transposed norm_t[i][c] ----------------
__global__ __launch_bounds__(256) void normalize_t(const float* __restrict__ x,
                                                   const float* __restrict__ partial,
                                                   const float* __restrict__ scale,
                                                   const float* __restrict__ shift,
                                                   short* __restrict__ norm_t) {
    __shared__ float gm[8], gr[8];
    __shared__ float Aa[64], Bb[64];
    __shared__ short tile[32 * 66];
    int i0 = blockIdx.x * 32;
    int c0 = blockIdx.y * 64;
    int g0 = c0 >> 3;
    int t = threadIdx.x;
    if (t < 8) {
        float s = 0.f, ss = 0.f;
        #pragma unroll
        for (int ch = 0; ch < 8; ++ch) {
            s += partial[((g0 + t) * 8 + ch) * 2];
            ss += partial[((g0 + t) * 8 + ch) * 2 + 1];
        }
        float mean = s * (1.0f / 32768.0f);
        float var = ss * (1.0f / 32768.0f) - mean * mean;
        gm[t] = mean;
        gr[t] = rsqrtf(var + 1e-6f);
    }
    __syncthreads();
    if (t < 64) {
        int c = c0 + t;
        float a = gr[t >> 3] * (1.0f + scale[c]);
        Aa[t] = a;
        Bb[t] = shift[c] - gm[t >> 3] * a;
    }
    __syncthreads();
    #pragma unroll
    for (int e0 = 0; e0 < 8; ++e0) {
        int e = e0 * 256 + t;
        int cl = e >> 5, il = e & 31;
        float v = x[(c0 + cl) * NN + i0 + il];
        tile[il * 66 + cl] = f2bf(v * Aa[cl] + Bb[cl]);
    }
    __syncthreads();
    #pragma unroll
    for (int e0 = 0; e0 < 4; ++e0) {
        int e = e0 * 256 + t;
        int il = e >> 5, cd = e & 31;
        uint32_t d = *(const uint32_t*)&tile[il * 66 + 2 * cd];
        *(uint32_t*)&norm_t[(i0 + il) * 256 + c0 + 2 * cd] = d;
    }
}

// ---------------- QKV GEMM: wave = 32o x 16i, grid (24, 64) ----------------
// Q pre-scaled by log2(e)/16 so attention can use exp2 directly.
__global__ __launch_bounds__(256) void qkv_gemm(const short* __restrict__ wqb,
                                                const short* __restrict__ norm_t,
                                                short* __restrict__ qtb, short* __restrict__ ktb,
                                                short* __restrict__ vcb) {
    int t = threadIdx.x;
    int w = t >> 6, lane = t & 63, li = lane & 15, lg = lane >> 4;
    int o0 = blockIdx.x * 32;
    int i0 = blockIdx.y * 64 + w * 16;
    f32x4 acc[2] = {{0,0,0,0},{0,0,0,0}};
    const short* bbase = norm_t + (i0 + li) * 256 + 8 * lg;
    const short* abase = wqb + (o0 + li) * 256 + 8 * lg;
    #pragma unroll
    for (int ks = 0; ks < 8; ++ks) {
        short8 bfrag = *(const short8*)(bbase + ks * 32);
        #pragma unroll
        for (int f = 0; f < 2; ++f) {
            short8 afrag = *(const short8*)(abase + f * 16 * 256 + ks * 32);
            acc[f] = __builtin_amdgcn_mfma_f32_16x16x32_bf16(afrag, bfrag, acc[f], 0, 0, 0);
        }
    }
    int i = i0 + li;
    #pragma unroll
    for (int f = 0; f < 2; ++f) {
        #pragma unroll
        for (int r = 0; r < 4; ++r) {
            int o = o0 + 16 * f + 4 * lg + r;
            float v = acc[f][r];
            int h = o / 96;
            int rr = o - h * 96;
            int cc = rr & 31;
            int kind = rr >> 5;
            if (kind == 0)      qtb[(h * NN + i) * 32 + cc] = f2bf(v * (0.0625f * 1.44269504f));
            else if (kind == 1) ktb[(h * NN + i) * 32 + cc] = f2bf(v);
            else                vcb[(h * 32 + cc) * NN + i] = f2bf(v);
        }
    }
}

// ---------------- flash attention: r12 pipeline + 2-subtile interleave, split acc ----
// grid 512: h = bid&7 (XCD pin), qb = (bid>>3)&15 (256 q/block), kh = bid>>7 (0..3).
// 8 stages of 128 keys; 3 stage buffers (48 KB LDS); waves 0-3 stage K, 4-7 stage V.
// COMPUTE interleaves the two halves of each chunk: both QK-MFMA pairs issue
// back-to-back (independent), then exp/pack/PV of A runs in the shadow of B's QK;
// PV accumulates into accE/accO to break the single-acc MFMA dependency chain.
__global__ __launch_bounds__(512, 4) void attention_mfma(const short* __restrict__ qtb,
                                                         const short* __restrict__ ktb,
                                                         const short* __restrict__ vcb,
                                                         float* __restrict__ pacc,
                                                         float* __restrict__ plsum) {
    __shared__ __align__(16) char lds[49152];

    int bid = blockIdx.x;
    int h = bid & 7;
    int qb = (bid >> 3) & 15;
    int kh = bid >> 7;
    int t = threadIdx.x;
    int w = t >> 6, lane = t & 63, l31 = lane & 31, hi = lane >> 5;

    int qbase = qb * 256 + w * 32;
    const short* qrow = qtb + (h * NN + qbase + l31) * 32;
    short8 qf0 = *(const short8*)(qrow + 8 * hi);        // c 0..15 half
    short8 qf1 = *(const short8*)(qrow + 16 + 8 * hi);   // c 16..31 half
    asm volatile("s_waitcnt vmcnt(0)" ::: "memory");

    const char* src0;
    const char* src1;
    int ldsoff0, ldsoff1, step;
    if (w < 4) {
        int row_l = lane >> 2, g_lds = lane & 3;
        int g_glob = g_lds ^ (row_l & 3);
        const char* kbase = (const char*)ktb + (size_t)(h * NN + kh * 1024) * 64;
        int s0 = 2 * w, s1 = 2 * w + 1;
        src0 = kbase + ((s0 >> 2) * 64 + (s0 & 3) * 16 + row_l) * 64 + g_glob * 16;
        src1 = kbase + ((s1 >> 2) * 64 + (s1 & 3) * 16 + row_l) * 64 + g_glob * 16;
        ldsoff0 = s0 * 1024;
        ldsoff1 = s1 * 1024;
        step = 8192;
    } else {
        int row_l = lane >> 3, vs_lds = lane & 7;
        int vg = vs_lds ^ row_l;
        const char* vbase = (const char*)vcb + (size_t)(h * 32) * (NN * 2) + kh * 2048;
        int s0 = 2 * (w - 4), s1 = 2 * (w - 4) + 1;
        src0 = vbase + (size_t)((s0 & 3) * 8 + row_l) * (NN * 2) + (s0 >> 2) * 128 + vg * 16;
        src1 = vbase + (size_t)((s1 & 3) * 8 + row_l) * (NN * 2) + (s1 >> 2) * 128 + vg * 16;
        ldsoff0 = 8192 + s0 * 1024;
        ldsoff1 = 8192 + s1 * 1024;
        step = 256;
    }

    f32x16 accE = {0,0,0,0,0,0,0,0,0,0,0,0,0,0,0,0};
    f32x16 accO = {0,0,0,0,0,0,0,0,0,0,0,0,0,0,0,0};
    const f32x16 zero16 = {0,0,0,0,0,0,0,0,0,0,0,0,0,0,0,0};
    float lsum = 0.f;

    #define ISSUE(st, b) do { \
        __builtin_amdgcn_global_load_lds((const uint32_t*)(src0 + (st) * step), \
            (uint32_t*)(lds + (b) * 16384 + ldsoff0), 16, 0, 0); \
        __builtin_amdgcn_global_load_lds((const uint32_t*)(src1 + (st) * step), \
            (uint32_t*)(lds + (b) * 16384 + ldsoff1), 16, 0, 0); \
    } while (0)

    // exp -> lsum -> pack -> PV for one S tile, into the given accumulator
    #define FINISH(S, vv0, vv1, ACC) do { \
        float p[16]; \
        _Pragma("unroll") \
        for (int r = 0; r < 16; ++r) p[r] = __builtin_amdgcn_exp2f((S)[r]); \
        float u0 = 0.f, u1 = 0.f; \
        _Pragma("unroll") \
        for (int r = 0; r < 4; ++r) { u0 += p[r] + p[4 + r]; u1 += p[8 + r] + p[12 + r]; } \
        lsum += u0 + u1; \
        auto A1 = __builtin_amdgcn_permlane32_swap(cvt_pk_bf16(p[0], p[1]),   cvt_pk_bf16(p[4], p[5]),   false, false); \
        auto A2 = __builtin_amdgcn_permlane32_swap(cvt_pk_bf16(p[2], p[3]),   cvt_pk_bf16(p[6], p[7]),   false, false); \
        auto A3 = __builtin_amdgcn_permlane32_swap(cvt_pk_bf16(p[8], p[9]),   cvt_pk_bf16(p[12], p[13]), false, false); \
        auto A4 = __builtin_amdgcn_permlane32_swap(cvt_pk_bf16(p[10], p[11]), cvt_pk_bf16(p[14], p[15]), false, false); \
        union PF { uint32_t u[4]; short8 s8; }; \
        PF f1, f2; \
        f1.u[0] = A1[0]; f1.u[1] = A2[0]; f1.u[2] = A1[1]; f1.u[3] = A2[1]; \
        f2.u[0] = A3[0]; f2.u[1] = A4[0]; f2.u[2] = A3[1]; f2.u[3] = A4[1]; \
        __builtin_amdgcn_s_setprio(1); \
        ACC = __builtin_amdgcn_mfma_f32_32x32x16_bf16(vv0, f1.s8, ACC, 0, 0, 0); \
        ACC = __builtin_amdgcn_mfma_f32_32x32x16_bf16(vv1, f2.s8, ACC, 0, 0, 0); \
        __builtin_amdgcn_s_setprio(0); \
    } while (0)

    #define COMPUTE(b) do { \
        const char* bb_ = lds + (b) * 16384; \
        _Pragma("unroll") \
        for (int chunk = 0; chunk < 2; ++chunk) { \
            int cx = l31 & 7; \
            const char* vr = bb_ + 8192 + chunk * 4096 + l31 * 128; \
            /* subtile A = half 0 (j 0..31), subtile B = half 1 (j 32..63) */ \
            int RA = l31;           int rxA = RA & 3; \
            int RB = 32 + l31;      int rxB = RB & 3; \
            const char* krA = bb_ + chunk * 4096 + RA * 64; \
            const char* krB = bb_ + chunk * 4096 + RB * 64; \
            short8 kfA0 = *(const short8*)(krA + ((hi ^ rxA) << 4)); \
            short8 kfA1 = *(const short8*)(krA + (((2 + hi) ^ rxA) << 4)); \
            short8 kfB0 = *(const short8*)(krB + ((hi ^ rxB) << 4)); \
            short8 kfB1 = *(const short8*)(krB + (((2 + hi) ^ rxB) << 4)); \
            int svA = hi, svB = 4 + hi; \
            short8 vfA0 = *(const short8*)(vr + ((svA ^ cx) << 4)); \
            short8 vfA1 = *(const short8*)(vr + (((svA + 2) ^ cx) << 4)); \
            short8 vfB0 = *(const short8*)(vr + ((svB ^ cx) << 4)); \
            short8 vfB1 = *(const short8*)(vr + (((svB + 2) ^ cx) << 4)); \
            /* both QK pairs issued back-to-back: B's MFMAs overlap A's finish */ \
            __builtin_amdgcn_s_setprio(1); \
            f32x16 sA = __builtin_amdgcn_mfma_f32_32x32x16_bf16(kfA0, qf0, zero16, 0, 0, 0); \
            sA = __builtin_amdgcn_mfma_f32_32x32x16_bf16(kfA1, qf1, sA, 0, 0, 0); \
            f32x16 sB = __builtin_amdgcn_mfma_f32_32x32x16_bf16(kfB0, qf0, zero16, 0, 0, 0); \
            sB = __builtin_amdgcn_mfma_f32_32x32x16_bf16(kfB1, qf1, sB, 0, 0, 0); \
            __builtin_amdgcn_s_setprio(0); \
            FINISH(sA, vfA0, vfA1, accE); \
            FINISH(sB, vfB0, vfB1, accO); \
        } \
    } while (0)

    ISSUE(0, 0);
    ISSUE(1, 1);
    ISSUE(2, 2);
    asm volatile("s_waitcnt vmcnt(4)" ::: "memory");
    __builtin_amdgcn_s_barrier();

    #pragma unroll
    for (int st = 0; st < 5; ++st) {
        COMPUTE(st % 3);
        __builtin_amdgcn_s_barrier();
        ISSUE(st + 3, st % 3);
        asm volatile("s_waitcnt vmcnt(4)" ::: "memory");
        __builtin_amdgcn_s_barrier();
    }
    COMPUTE(2);   // stage 5
    __builtin_amdgcn_s_barrier();
    asm volatile("s_waitcnt vmcnt(2)" ::: "memory");
    __builtin_amdgcn_s_barrier();
    COMPUTE(0);   // stage 6
    __builtin_amdgcn_s_barrier();
    asm volatile("s_waitcnt vmcnt(0)" ::: "memory");
    __builtin_amdgcn_s_barrier();
    COMPUTE(1);   // stage 7

    #undef ISSUE
    #undef FINISH
    #undef COMPUTE

    lsum += __shfl_xor(lsum, 32);

    // partial outputs: pacc[(kh*8+h)*32 + c][i] coalesced f32 rows, plsum[(kh*8+h)][i]
    int qg = qbase + l31;
    float* pb = pacc + (size_t)((kh * 8 + h) * 32) * NN + qg;
    #pragma unroll
    for (int r = 0; r < 16; ++r) {
        int c = (r & 3) + 8 * (r >> 2) + 4 * hi;
        pb[c * NN] = accE[r] + accO[r];
    }
    if (hi == 0) plsum[(size_t)(kh * 8 + h) * NN + qg] = lsum;
}

// ---------------- merge the four key-quarter partials -> attnT bf16 [i][c] ----------------
__global__ __launch_bounds__(256) void attn_merge(const float* __restrict__ pacc,
                                                  const float* __restrict__ plsum,
                                                  short* __restrict__ attnT) {
    __shared__ float tile[64][33];
    __shared__ float invl[64];
    int it = blockIdx.x;          // i-tile (64 queries)
    int h = blockIdx.y;
    int t = threadIdx.x;
    int i0 = it * 64;
    int c = t >> 3, ic = (t & 7) * 8;
    const float* p0 = pacc + (size_t)(h * 32 + c) * NN + i0 + ic;
    #pragma unroll
    for (int k = 0; k < 8; ++k) {
        float s = 0.f;
        #pragma unroll
        for (int q4 = 0; q4 < 4; ++q4) s += p0[(size_t)q4 * 8 * 32 * NN + k];
        tile[ic + k][c] = s;
    }
    if (t < 64) {
        float ls = 0.f;
        #pragma unroll
        for (int q4 = 0; q4 < 4; ++q4) ls += plsum[(size_t)(q4 * 8 + h) * NN + i0 + t];
        invl[t] = 1.0f / ls;
    }
    __syncthreads();
    int i = t >> 2, cs = (t & 3) * 8;
    float iv = invl[i];
    const float* tr = &tile[i][cs];
    uint4 o;
    o.x = cvt_pk_bf16(tr[0] * iv, tr[1] * iv);
    o.y = cvt_pk_bf16(tr[2] * iv, tr[3] * iv);
    o.z = cvt_pk_bf16(tr[4] * iv, tr[5] * iv);
    o.w = cvt_pk_bf16(tr[6] * iv, tr[7] * iv);
    *(uint4*)&attnT[(i0 + i) * 256 + h * 32 + cs] = o;
}

// ---------------- out projection GEMM + bias + residual: wave = 32o x 16i ----------------
__global__ __launch_bounds__(256) void proj_gemm(const short* __restrict__ wob,
                                                 const short* __restrict__ attnT,
                                                 const float* __restrict__ b_out,
                                                 const float* __restrict__ x,
                                                 float* __restrict__ out) {
    int t = threadIdx.x;
    int w = t >> 6, lane = t & 63, li = lane & 15, lg = lane >> 4;
    int o0 = blockIdx.x * 32;
    int i0 = blockIdx.y * 64 + w * 16;
    f32x4 acc[2] = {{0,0,0,0},{0,0,0,0}};
    const short* bbase = attnT + (i0 + li) * 256 + 8 * lg;
    const short* abase = wob + (o0 + li) * 256 + 8 * lg;
    #pragma unroll
    for (int ks = 0; ks < 8; ++ks) {
        short8 bfrag = *(const short8*)(bbase + ks * 32);
        #pragma unroll
        for (int f = 0; f < 2; ++f) {
            short8 afrag = *(const short8*)(abase + f * 16 * 256 + ks * 32);
            acc[f] = __builtin_amdgcn_mfma_f32_16x16x32_bf16(afrag, bfrag, acc[f], 0, 0, 0);
        }
    }
    int i = i0 + li;
    #pragma unroll
    for (int f = 0; f < 2; ++f) {
        #pragma unroll
        for (int r = 0; r < 4; ++r) {
            int o = o0 + 16 * f + 4 * lg + r;
            out[o * NN + i] = acc[f][r] + b_out[o] + x[o * NN + i];
        }
    }
}

extern "C" void kernel_launch(void* const* d_in, const int* in_sizes, int n_in,
                              void* d_out, int out_size, void* d_ws, size_t ws_size,
                              hipStream_t stream) {
    const float* x       = (const float*)d_in[0];
    const float* cond    = (const float*)d_in[1];
    const float* w_scale = (const float*)d_in[2];
    const float* b_scale = (const float*)d_in[3];
    const float* w_shift = (const float*)d_in[4];
    const float* b_shift = (const float*)d_in[5];
    const float* w_qkv   = (const float*)d_in[6];
    const float* w_out   = (const float*)d_in[7];
    const float* b_out   = (const float*)d_in[8];
    float* out = (float*)d_out;

    float* ws = (float*)d_ws;
    float* scale   = ws;            // 256
    float* shift   = ws + 256;      // 256
    float* partial = ws + 512;      // 512
    short* norm_t = (short*)(ws + 1024);     // [i][c] 1M bf16
    short* qtb = norm_t + 1048576;           // [h][i][c] (scaled by log2e/16)
    short* ktb = qtb + 1048576;              // [h][j][c]
    short* vcb = ktb + 1048576;              // [h][c][j]
    short* attnT = vcb + 1048576;            // [i][c] 1M bf16
    short* wqb = attnT + 1048576;            // 768*256
    short* wob = wqb + 196608;               // 256*256
    float* pacc  = (float*)(wob + 65536);    // [4][8][32][4096] f32 = 16 MB
    float* plsum = pacc + (size_t)4 * 8 * 32 * NN;   // [4][8][4096] f32

    front_fused<<<1344, 256, 0, stream>>>(x, cond, w_scale, b_scale, w_shift, b_shift,
                                          w_qkv, w_out, partial, scale, shift, wqb, wob);
    normalize_t<<<dim3(128, 4), 256, 0, stream>>>(x, partial, scale, shift, norm_t);
    qkv_gemm<<<dim3(24, 64), 256, 0, stream>>>(wqb, norm_t, qtb, ktb, vcb);
    attention_mfma<<<512, 512, 0, stream>>>(qtb, ktb, vcb, pacc, plsum);
    attn_merge<<<dim3(64, 8), 256, 0, stream>>>(pacc, plsum, attnT);
    proj_gemm<<<dim3(8, 64), 256, 0, stream>>>(wob, attnT, b_out, x, out);
}

// Round 22
// 70.189 us; speedup vs baseline: 1.0112x; 1.0112x over previous
//
#include <hip/hip_runtime.h>
#include <math.h>

#define CCH 256
#define NN  4096
#define NHEAD 8
#define CONDD 512

typedef __attribute__((ext_vector_type(8))) short short8;
typedef __attribute__((ext_vector_type(4))) float f32x4;
typedef __attribute__((ext_vector_type(16))) float f32x16;

static __device__ __forceinline__ short f2bf(float f) {
    union { float f; uint32_t u; } v; v.f = f;
    uint32_t r = v.u + 0x7fffu + ((v.u >> 16) & 1u);   // RNE
    return (short)(r >> 16);
}

static __device__ __forceinline__ uint32_t cvt_pk_bf16(float a, float b) {
    uint32_t r;
    asm("v_cvt_pk_bf16_f32 %0, %1, %2" : "=v"(r) : "v"(a), "v"(b));
    return r;
}

// ---------------- fused front: group stats | weight conv | adagn linear ----------------
__global__ __launch_bounds__(256) void front_fused(const float* __restrict__ x,
                                                   const float* __restrict__ cond,
                                                   const float* __restrict__ w_scale,
                                                   const float* __restrict__ b_scale,
                                                   const float* __restrict__ w_shift,
                                                   const float* __restrict__ b_shift,
                                                   const float* __restrict__ wq,
                                                   const float* __restrict__ wo,
                                                   float* __restrict__ partial,
                                                   float* __restrict__ scale,
                                                   float* __restrict__ shift,
                                                   short* __restrict__ wqb,
                                                   short* __restrict__ wob) {
    __shared__ float rs[4], rss[4];
    int bb = blockIdx.x;
    int t = threadIdx.x;
    if (bb < 256) {
        const float4* p = (const float4*)(x + bb * 4096);
        float s = 0.f, ss = 0.f;
        for (int k = t; k < 1024; k += 256) {
            float4 v = p[k];
            s += v.x + v.y + v.z + v.w;
            ss += v.x * v.x + v.y * v.y + v.z * v.z + v.w * v.w;
        }
        #pragma unroll
        for (int off = 32; off; off >>= 1) { s += __shfl_xor(s, off); ss += __shfl_xor(ss, off); }
        int wid = t >> 6;
        if ((t & 63) == 0) { rs[wid] = s; rss[wid] = ss; }
        __syncthreads();
        if (t == 0) {
            partial[2 * bb] = rs[0] + rs[1] + rs[2] + rs[3];
            partial[2 * bb + 1] = rss[0] + rss[1] + rss[2] + rss[3];
        }
    } else if (bb < 1280) {
        int idx = (bb - 256) * 256 + t;
        if (idx < 196608) wqb[idx] = f2bf(wq[idx]);
        else              wob[idx - 196608] = f2bf(wo[idx - 196608]);
    } else {
        int o = (bb - 1280) * 4 + (t >> 6);
        int lane = t & 63;
        float ds = 0.f, dh = 0.f;
        for (int k = lane; k < CONDD; k += 64) {
            float cv = cond[k];
            ds += cv * w_scale[o * CONDD + k];
            dh += cv * w_shift[o * CONDD + k];
        }
        #pragma unroll
        for (int off = 32; off; off >>= 1) { ds += __shfl_xor(ds, off); dh += __shfl_xor(dh, off); }
        if (lane == 0) { scale[o] = ds + b_scale[o]; shift[o] = dh + b_shift[o]; }
    }
}

// ---------------- normalize + affine -> bf16 transposed norm_t[i][c] ----------------
__global__ __launch_bounds__(256) void normalize_t(const float* __restrict__ x,
                                                   const float* __restrict__ partial,
                                                   const float* __restrict__ scale,
                                                   const float* __restrict__ shift,
                                                   short* __restrict__ norm_t) {
    __shared__ float gm[8], gr[8];
    __shared__ float Aa[64], Bb[64];
    __shared__ short tile[32 * 66];
    int i0 = blockIdx.x * 32;
    int c0 = blockIdx.y * 64;
    int g0 = c0 >> 3;
    int t = threadIdx.x;
    if (t < 8) {
        float s = 0.f, ss = 0.f;
        #pragma unroll
        for (int ch = 0; ch < 8; ++ch) {
            s += partial[((g0 + t) * 8 + ch) * 2];
            ss += partial[((g0 + t) * 8 + ch) * 2 + 1];
        }
        float mean = s * (1.0f / 32768.0f);
        float var = ss * (1.0f / 32768.0f) - mean * mean;
        gm[t] = mean;
        gr[t] = rsqrtf(var + 1e-6f);
    }
    __syncthreads();
    if (t < 64) {
        int c = c0 + t;
        float a = gr[t >> 3] * (1.0f + scale[c]);
        Aa[t] = a;
        Bb[t] = shift[c] - gm[t >> 3] * a;
    }
    __syncthreads();
    #pragma unroll
    for (int e0 = 0; e0 < 8; ++e0) {
        int e = e0 * 256 + t;
        int cl = e >> 5, il = e & 31;
        float v = x[(c0 + cl) * NN + i0 + il];
        tile[il * 66 + cl] = f2bf(v * Aa[cl] + Bb[cl]);
    }
    __syncthreads();
    #pragma unroll
    for (int e0 = 0; e0 < 4; ++e0) {
        int e = e0 * 256 + t;
        int il = e >> 5, cd = e & 31;
        uint32_t d = *(const uint32_t*)&tile[il * 66 + 2 * cd];
        *(uint32_t*)&norm_t[(i0 + il) * 256 + c0 + 2 * cd] = d;
    }
}

// ---------------- QKV GEMM: wave = 32o x 16i, grid (24, 64) ----------------
// Q pre-scaled by log2(e)/16 so attention can use exp2 directly.
__global__ __launch_bounds__(256) void qkv_gemm(const short* __restrict__ wqb,
                                                const short* __restrict__ norm_t,
                                                short* __restrict__ qtb, short* __restrict__ ktb,
                                                short* __restrict__ vcb) {
    int t = threadIdx.x;
    int w = t >> 6, lane = t & 63, li = lane & 15, lg = lane >> 4;
    int o0 = blockIdx.x * 32;
    int i0 = blockIdx.y * 64 + w * 16;
    f32x4 acc[2] = {{0,0,0,0},{0,0,0,0}};
    const short* bbase = norm_t + (i0 + li) * 256 + 8 * lg;
    const short* abase = wqb + (o0 + li) * 256 + 8 * lg;
    #pragma unroll
    for (int ks = 0; ks < 8; ++ks) {
        short8 bfrag = *(const short8*)(bbase + ks * 32);
        #pragma unroll
        for (int f = 0; f < 2; ++f) {
            short8 afrag = *(const short8*)(abase + f * 16 * 256 + ks * 32);
            acc[f] = __builtin_amdgcn_mfma_f32_16x16x32_bf16(afrag, bfrag, acc[f], 0, 0, 0);
        }
    }
    int i = i0 + li;
    #pragma unroll
    for (int f = 0; f < 2; ++f) {
        #pragma unroll
        for (int r = 0; r < 4; ++r) {
            int o = o0 + 16 * f + 4 * lg + r;
            float v = acc[f][r];
            int h = o / 96;
            int rr = o - h * 96;
            int cc = rr & 31;
            int kind = rr >> 5;
            if (kind == 0)      qtb[(h * NN + i) * 32 + cc] = f2bf(v * (0.0625f * 1.44269504f));
            else if (kind == 1) ktb[(h * NN + i) * 32 + cc] = f2bf(v);
            else                vcb[(h * 32 + cc) * NN + i] = f2bf(v);
        }
    }
}

// ---------------- flash attention: r12 core WITHOUT s_setprio (isolated A/B) ----------
// grid 512: h = bid&7 (XCD pin), qb = (bid>>3)&15 (256 q/block), kh = bid>>7 (0..3).
// 8 stages of 128 keys; 3 stage buffers (48 KB LDS); waves 0-3 stage K, 4-7 stage V.
// s_setprio removed: on this lockstep schedule it has no role-split to arbitrate and
// may starve the co-resident block's waves (m190 evidence).
__global__ __launch_bounds__(512, 4) void attention_mfma(const short* __restrict__ qtb,
                                                         const short* __restrict__ ktb,
                                                         const short* __restrict__ vcb,
                                                         float* __restrict__ pacc,
                                                         float* __restrict__ plsum) {
    __shared__ __align__(16) char lds[49152];

    int bid = blockIdx.x;
    int h = bid & 7;
    int qb = (bid >> 3) & 15;
    int kh = bid >> 7;
    int t = threadIdx.x;
    int w = t >> 6, lane = t & 63, l31 = lane & 31, hi = lane >> 5;

    int qbase = qb * 256 + w * 32;
    const short* qrow = qtb + (h * NN + qbase + l31) * 32;
    short8 qf0 = *(const short8*)(qrow + 8 * hi);        // c 0..15 half
    short8 qf1 = *(const short8*)(qrow + 16 + 8 * hi);   // c 16..31 half
    asm volatile("s_waitcnt vmcnt(0)" ::: "memory");

    const char* src0;
    const char* src1;
    int ldsoff0, ldsoff1, step;
    if (w < 4) {
        int row_l = lane >> 2, g_lds = lane & 3;
        int g_glob = g_lds ^ (row_l & 3);
        const char* kbase = (const char*)ktb + (size_t)(h * NN + kh * 1024) * 64;
        int s0 = 2 * w, s1 = 2 * w + 1;
        src0 = kbase + ((s0 >> 2) * 64 + (s0 & 3) * 16 + row_l) * 64 + g_glob * 16;
        src1 = kbase + ((s1 >> 2) * 64 + (s1 & 3) * 16 + row_l) * 64 + g_glob * 16;
        ldsoff0 = s0 * 1024;
        ldsoff1 = s1 * 1024;
        step = 8192;
    } else {
        int row_l = lane >> 3, vs_lds = lane & 7;
        int vg = vs_lds ^ row_l;
        const char* vbase = (const char*)vcb + (size_t)(h * 32) * (NN * 2) + kh * 2048;
        int s0 = 2 * (w - 4), s1 = 2 * (w - 4) + 1;
        src0 = vbase + (size_t)((s0 & 3) * 8 + row_l) * (NN * 2) + (s0 >> 2) * 128 + vg * 16;
        src1 = vbase + (size_t)((s1 & 3) * 8 + row_l) * (NN * 2) + (s1 >> 2) * 128 + vg * 16;
        ldsoff0 = 8192 + s0 * 1024;
        ldsoff1 = 8192 + s1 * 1024;
        step = 256;
    }

    f32x16 acc = {0,0,0,0,0,0,0,0,0,0,0,0,0,0,0,0};
    const f32x16 zero16 = {0,0,0,0,0,0,0,0,0,0,0,0,0,0,0,0};
    float lsum = 0.f;

    #define ISSUE(st, b) do { \
        __builtin_amdgcn_global_load_lds((const uint32_t*)(src0 + (st) * step), \
            (uint32_t*)(lds + (b) * 16384 + ldsoff0), 16, 0, 0); \
        __builtin_amdgcn_global_load_lds((const uint32_t*)(src1 + (st) * step), \
            (uint32_t*)(lds + (b) * 16384 + ldsoff1), 16, 0, 0); \
    } while (0)

    #define COMPUTE(b) do { \
        const char* bb_ = lds + (b) * 16384; \
        _Pragma("unroll") \
        for (int chunk = 0; chunk < 2; ++chunk) { \
            _Pragma("unroll") \
            for (int half = 0; half < 2; ++half) { \
                int jl = half * 32; \
                int R = jl + l31; \
                int rx = R & 3; \
                const char* kr = bb_ + chunk * 4096 + R * 64; \
                short8 kf0 = *(const short8*)(kr + (((hi) ^ rx) << 4)); \
                short8 kf1 = *(const short8*)(kr + (((2 + hi) ^ rx) << 4)); \
                const char* vr = bb_ + 8192 + chunk * 4096 + l31 * 128; \
                int cx = l31 & 7; \
                int sv = (jl >> 3) + hi; \
                short8 vf0 = *(const short8*)(vr + ((sv ^ cx) << 4)); \
                short8 vf1 = *(const short8*)(vr + (((sv + 2) ^ cx) << 4)); \
                f32x16 s = __builtin_amdgcn_mfma_f32_32x32x16_bf16(kf0, qf0, zero16, 0, 0, 0); \
                s = __builtin_amdgcn_mfma_f32_32x32x16_bf16(kf1, qf1, s, 0, 0, 0); \
                float p[16]; \
                _Pragma("unroll") \
                for (int r = 0; r < 16; ++r) p[r] = __builtin_amdgcn_exp2f(s[r]); \
                float u0 = 0.f, u1 = 0.f; \
                _Pragma("unroll") \
                for (int r = 0; r < 4; ++r) { u0 += p[r] + p[4 + r]; u1 += p[8 + r] + p[12 + r]; } \
                lsum += u0 + u1; \
                auto A1 = __builtin_amdgcn_permlane32_swap(cvt_pk_bf16(p[0], p[1]),   cvt_pk_bf16(p[4], p[5]),   false, false); \
                auto A2 = __builtin_amdgcn_permlane32_swap(cvt_pk_bf16(p[2], p[3]),   cvt_pk_bf16(p[6], p[7]),   false, false); \
                auto A3 = __builtin_amdgcn_permlane32_swap(cvt_pk_bf16(p[8], p[9]),   cvt_pk_bf16(p[12], p[13]), false, false); \
                auto A4 = __builtin_amdgcn_permlane32_swap(cvt_pk_bf16(p[10], p[11]), cvt_pk_bf16(p[14], p[15]), false, false); \
                union PF { uint32_t u[4]; short8 s8; }; \
                PF f1, f2; \
                f1.u[0] = A1[0]; f1.u[1] = A2[0]; f1.u[2] = A1[1]; f1.u[3] = A2[1]; \
                f2.u[0] = A3[0]; f2.u[1] = A4[0]; f2.u[2] = A3[1]; f2.u[3] = A4[1]; \
                acc = __builtin_amdgcn_mfma_f32_32x32x16_bf16(vf0, f1.s8, acc, 0, 0, 0); \
                acc = __builtin_amdgcn_mfma_f32_32x32x16_bf16(vf1, f2.s8, acc, 0, 0, 0); \
            } \
        } \
    } while (0)

    ISSUE(0, 0);
    ISSUE(1, 1);
    ISSUE(2, 2);
    asm volatile("s_waitcnt vmcnt(4)" ::: "memory");
    __builtin_amdgcn_s_barrier();

    #pragma unroll
    for (int st = 0; st < 5; ++st) {
        COMPUTE(st % 3);
        __builtin_amdgcn_s_barrier();
        ISSUE(st + 3, st % 3);
        asm volatile("s_waitcnt vmcnt(4)" ::: "memory");
        __builtin_amdgcn_s_barrier();
    }
    COMPUTE(2);   // stage 5
    __builtin_amdgcn_s_barrier();
    asm volatile("s_waitcnt vmcnt(2)" ::: "memory");
    __builtin_amdgcn_s_barrier();
    COMPUTE(0);   // stage 6
    __builtin_amdgcn_s_barrier();
    asm volatile("s_waitcnt vmcnt(0)" ::: "memory");
    __builtin_amdgcn_s_barrier();
    COMPUTE(1);   // stage 7

    #undef ISSUE
    #undef COMPUTE

    lsum += __shfl_xor(lsum, 32);

    // partial outputs: pacc[(kh*8+h)*32 + c][i] coalesced f32 rows, plsum[(kh*8+h)][i]
    int qg = qbase + l31;
    float* pb = pacc + (size_t)((kh * 8 + h) * 32) * NN + qg;
    #pragma unroll
    for (int r = 0; r < 16; ++r) {
        int c = (r & 3) + 8 * (r >> 2) + 4 * hi;
        pb[c * NN] = acc[r];
    }
    if (hi == 0) plsum[(size_t)(kh * 8 + h) * NN + qg] = lsum;
}

// ---------------- merge the four key-quarter partials -> attnT bf16 [i][c] ----------------
__global__ __launch_bounds__(256) void attn_merge(const float* __restrict__ pacc,
                                                  const float* __restrict__ plsum,
                                                  short* __restrict__ attnT) {
    __shared__ float tile[64][33];
    __shared__ float invl[64];
    int it = blockIdx.x;          // i-tile (64 queries)
    int h = blockIdx.y;
    int t = threadIdx.x;
    int i0 = it * 64;
    int c = t >> 3, ic = (t & 7) * 8;
    const float* p0 = pacc + (size_t)(h * 32 + c) * NN + i0 + ic;
    #pragma unroll
    for (int k = 0; k < 8; ++k) {
        float s = 0.f;
        #pragma unroll
        for (int q4 = 0; q4 < 4; ++q4) s += p0[(size_t)q4 * 8 * 32 * NN + k];
        tile[ic + k][c] = s;
    }
    if (t < 64) {
        float ls = 0.f;
        #pragma unroll
        for (int q4 = 0; q4 < 4; ++q4) ls += plsum[(size_t)(q4 * 8 + h) * NN + i0 + t];
        invl[t] = 1.0f / ls;
    }
    __syncthreads();
    int i = t >> 2, cs = (t & 3) * 8;
    float iv = invl[i];
    const float* tr = &tile[i][cs];
    uint4 o;
    o.x = cvt_pk_bf16(tr[0] * iv, tr[1] * iv);
    o.y = cvt_pk_bf16(tr[2] * iv, tr[3] * iv);
    o.z = cvt_pk_bf16(tr[4] * iv, tr[5] * iv);
    o.w = cvt_pk_bf16(tr[6] * iv, tr[7] * iv);
    *(uint4*)&attnT[(i0 + i) * 256 + h * 32 + cs] = o;
}

// ---------------- out projection GEMM + bias + residual: wave = 32o x 16i ----------------
__global__ __launch_bounds__(256) void proj_gemm(const short* __restrict__ wob,
                                                 const short* __restrict__ attnT,
                                                 const float* __restrict__ b_out,
                                                 const float* __restrict__ x,
                                                 float* __restrict__ out) {
    int t = threadIdx.x;
    int w = t >> 6, lane = t & 63, li = lane & 15, lg = lane >> 4;
    int o0 = blockIdx.x * 32;
    int i0 = blockIdx.y * 64 + w * 16;
    f32x4 acc[2] = {{0,0,0,0},{0,0,0,0}};
    const short* bbase = attnT + (i0 + li) * 256 + 8 * lg;
    const short* abase = wob + (o0 + li) * 256 + 8 * lg;
    #pragma unroll
    for (int ks = 0; ks < 8; ++ks) {
        short8 bfrag = *(const short8*)(bbase + ks * 32);
        #pragma unroll
        for (int f = 0; f < 2; ++f) {
            short8 afrag = *(const short8*)(abase + f * 16 * 256 + ks * 32);
            acc[f] = __builtin_amdgcn_mfma_f32_16x16x32_bf16(afrag, bfrag, acc[f], 0, 0, 0);
        }
    }
    int i = i0 + li;
    #pragma unroll
    for (int f = 0; f < 2; ++f) {
        #pragma unroll
        for (int r = 0; r < 4; ++r) {
            int o = o0 + 16 * f + 4 * lg + r;
            out[o * NN + i] = acc[f][r] + b_out[o] + x[o * NN + i];
        }
    }
}

extern "C" void kernel_launch(void* const* d_in, const int* in_sizes, int n_in,
                              void* d_out, int out_size, void* d_ws, size_t ws_size,
                              hipStream_t stream) {
    const float* x       = (const float*)d_in[0];
    const float* cond    = (const float*)d_in[1];
    const float* w_scale = (const float*)d_in[2];
    const float* b_scale = (const float*)d_in[3];
    const float* w_shift = (const float*)d_in[4];
    const float* b_shift = (const float*)d_in[5];
    const float* w_qkv   = (const float*)d_in[6];
    const float* w_out   = (const float*)d_in[7];
    const float* b_out   = (const float*)d_in[8];
    float* out = (float*)d_out;

    float* ws = (float*)d_ws;
    float* scale   = ws;            // 256
    float* shift   = ws + 256;      // 256
    float* partial = ws + 512;      // 512
    short* norm_t = (short*)(ws + 1024);     // [i][c] 1M bf16
    short* qtb = norm_t + 1048576;           // [h][i][c] (scaled by log2e/16)
    short* ktb = qtb + 1048576;              // [h][j][c]
    short* vcb = ktb + 1048576;              // [h][c][j]
    short* attnT = vcb + 1048576;            // [i][c] 1M bf16
    short* wqb = attnT + 1048576;            // 768*256
    short* wob = wqb + 196608;               // 256*256
    float* pacc  = (float*)(wob + 65536);    // [4][8][32][4096] f32 = 16 MB
    float* plsum = pacc + (size_t)4 * 8 * 32 * NN;   // [4][8][4096] f32

    front_fused<<<1344, 256, 0, stream>>>(x, cond, w_scale, b_scale, w_shift, b_shift,
                                          w_qkv, w_out, partial, scale, shift, wqb, wob);
    normalize_t<<<dim3(128, 4), 256, 0, stream>>>(x, partial, scale, shift, norm_t);
    qkv_gemm<<<dim3(24, 64), 256, 0, stream>>>(wqb, norm_t, qtb, ktb, vcb);
    attention_mfma<<<512, 512, 0, stream>>>(qtb, ktb, vcb, pacc, plsum);
    attn_merge<<<dim3(64, 8), 256, 0, stream>>>(pacc, plsum, attnT);
    proj_gemm<<<dim3(8, 64), 256, 0, stream>>>(wob, attnT, b_out, x, out);
}